// Round 3
// baseline (34692.313 us; speedup 1.0000x reference)
//
#include <hip/hip_runtime.h>
#include <hip/hip_cooperative_groups.h>

namespace cg = cooperative_groups;

typedef __attribute__((ext_vector_type(8))) _Float16 half8;
typedef __attribute__((ext_vector_type(4))) _Float16 half4;
typedef __attribute__((ext_vector_type(4))) float floatx4;

constexpr int T_STEPS = 1024, BATCH = 64, HID = 1024, IN_DIM = 5;
constexpr int NWG = 200;                       // 64 L1 + 128 L2 + 8 OUT
constexpr size_t LDS_BYTES = 131072;           // 128 KiB per WG (weights)

// Workspace: only h ping-pong buffers (c lives in registers).
constexpr size_t O_B1 = 0;                                   // h1 fp16 [2][64][1024]
constexpr size_t O_B2 = O_B1 + 2 * (size_t)BATCH * HID * 2;  // h2 fp16 [2][64][1024]
constexpr size_t WS_STATE = O_B2 + 2 * (size_t)BATCH * HID * 2;  // 512 KiB

__device__ __forceinline__ float sigf(float x)   { return 1.f / (1.f + __expf(-x)); }
__device__ __forceinline__ float tanhft(float x) { return 2.f / (1.f + __expf(-2.f * x)) - 1.f; }
__device__ __forceinline__ floatx4 mfma16(half8 a, half8 b, floatx4 c) {
    return __builtin_amdgcn_mfma_f32_16x16x32_f16(a, b, c, 0, 0, 0);
}
// T2 XOR swizzle: spread same-column reads of 2KB/4KB-strided rows across banks.
__device__ __forceinline__ int swz(int row, int kByte, int rowStrideB) {
    return row * rowStrideB + (kByte ^ ((row & 7) << 4));
}

__global__ void lstm_persistent(
    char* __restrict__ ws,
    const float* __restrict__ data, const int* __restrict__ lens,
    const float* __restrict__ Wih0, const float* __restrict__ Whh0,
    const float* __restrict__ bih0, const float* __restrict__ bhh0,
    const float* __restrict__ Wih1, const float* __restrict__ Whh1,
    const float* __restrict__ bih1, const float* __restrict__ bhh1,
    const float* __restrict__ Wout, const float* __restrict__ bout,
    float* __restrict__ out)
{
    extern __shared__ char smem[];
    cg::grid_group grid = cg::this_grid();

    _Float16* buf1 = (_Float16*)(ws + O_B1);
    _Float16* buf2 = (_Float16*)(ws + O_B2);

    const int bid  = blockIdx.x;
    const int tid  = threadIdx.x;
    const int lane = tid & 63;
    const int wv   = tid >> 6;
    const int lr   = lane & 15, lg = lane >> 4;

    // ---------------- init: stage weights into LDS, biases/x-weights into regs ----------------
    float creg[4] = {0.f, 0.f, 0.f, 0.f};
    float hreg[4] = {0.f, 0.f, 0.f, 0.f};
    int   lenr[4];
    float b0v = 0, b1v = 0, b2v = 0, b3v = 0;     // L1 gate biases / L2 base0,base1
    float w0[IN_DIM], w1[IN_DIM], w2[IN_DIM], w3[IN_DIM];  // L1 x-projection rows

    if (bid < 64) {
        // L1 WG: 16 units j0, 64 weight rows (r = g*16+u), K=1024, LDS [64][1024] fp16.
        const int j0 = bid * 16;
        for (int i = tid * 4; i < 64 * HID; i += 256 * 4) {
            int r = i >> 10, k = i & 1023;
            int gr = (r >> 4) * HID + j0 + (r & 15);
            const float4 w = *(const float4*)&Whh0[(size_t)gr * HID + k];
            half4 h4 = { (_Float16)w.x, (_Float16)w.y, (_Float16)w.z, (_Float16)w.w };
            *(half4*)(smem + swz(r, k * 2, 2048)) = h4;
        }
        const int j = j0 + lr;
        b0v = bih0[j] + bhh0[j];
        b1v = bih0[HID + j] + bhh0[HID + j];
        b2v = bih0[2 * HID + j] + bhh0[2 * HID + j];
        b3v = bih0[3 * HID + j] + bhh0[3 * HID + j];
        #pragma unroll
        for (int i = 0; i < IN_DIM; ++i) {
            w0[i] = Wih0[(0 * HID + j) * IN_DIM + i];
            w1[i] = Wih0[(1 * HID + j) * IN_DIM + i];
            w2[i] = Wih0[(2 * HID + j) * IN_DIM + i];
            w3[i] = Wih0[(3 * HID + j) * IN_DIM + i];
        }
        const int mb = wv * 16;
        #pragma unroll
        for (int r = 0; r < 4; ++r) lenr[r] = lens[mb + lg * 4 + r];
    } else if (bid < 192) {
        // L2 WG: 8 units j0, 32 rows (r = g*8+u), K=2048 ([Wih1|Whh1]), LDS [32][2048] fp16.
        const int j0 = (bid - 64) * 8;
        for (int i = tid * 4; i < 32 * 2048; i += 256 * 4) {
            int r = i >> 11, k = i & 2047;
            int gr = (r >> 3) * HID + j0 + (r & 7);
            const float* src = (k < HID) ? &Wih1[(size_t)gr * HID + k]
                                         : &Whh1[(size_t)gr * HID + (k - HID)];
            const float4 w = *(const float4*)src;
            half4 h4 = { (_Float16)w.x, (_Float16)w.y, (_Float16)w.z, (_Float16)w.w };
            *(half4*)(smem + swz(r, k * 2, 4096)) = h4;
        }
        {   // base0: LDS row lr (gates i/f); base1: LDS row 16+lr (gates g/o)
            int g0 = lr >> 3, u = lr & 7;
            b0v = bih1[g0 * HID + j0 + u] + bhh1[g0 * HID + j0 + u];
            b1v = bih1[(2 + g0) * HID + j0 + u] + bhh1[(2 + g0) * HID + j0 + u];
        }
        const int mb = wv * 16;
        #pragma unroll
        for (int r = 0; r < 4; ++r) lenr[r] = lens[mb + lg * 4 + r];
    } else {
        // OUT WG: stage Wout (5x1024 f32 = 20KB) into LDS.
        float* wlds = (float*)smem;
        for (int i = tid; i < IN_DIM * HID; i += 256) wlds[i] = Wout[i];
        const int ow = bid - 192;
        lenr[0] = lens[ow * 8 + wv * 2 + 0];
        lenr[1] = lens[ow * 8 + wv * 2 + 1];
    }
    __syncthreads();

    // ---------------- time loop: epoch e = L1 step e, L2 step e-1, OUT step e-2 ----------------
    for (int e = 0; e <= T_STEPS + 1; ++e) {
        if (bid < 64) {
            if (e < T_STEPS) {
                const int t = e;
                const int j0 = bid * 16, mb = wv * 16;
                const _Float16* hprev = buf1 + ((e + 1) & 1) * (BATCH * HID);
                _Float16*       hcur  = buf1 + (e & 1) * (BATCH * HID);
                floatx4 acc0 = {0,0,0,0}, acc1 = {0,0,0,0}, acc2 = {0,0,0,0}, acc3 = {0,0,0,0};
                const _Float16* ap = hprev + (mb + lr) * HID + lg * 8;
                #pragma unroll 4
                for (int kt = 0; kt < 32; ++kt) {
                    half8 a = *(const half8*)(ap + kt * 32);
                    const int kB = (kt * 32 + lg * 8) * 2;
                    acc0 = mfma16(a, *(const half8*)(smem + swz( 0 + lr, kB, 2048)), acc0);
                    acc1 = mfma16(a, *(const half8*)(smem + swz(16 + lr, kB, 2048)), acc1);
                    acc2 = mfma16(a, *(const half8*)(smem + swz(32 + lr, kB, 2048)), acc2);
                    acc3 = mfma16(a, *(const half8*)(smem + swz(48 + lr, kB, 2048)), acc3);
                }
                const int j = j0 + lr;
                #pragma unroll
                for (int r = 0; r < 4; ++r) {
                    const int b = mb + lg * 4 + r;
                    float gi = acc0[r] + b0v, gf = acc1[r] + b1v;
                    float gg = acc2[r] + b2v, go = acc3[r] + b3v;
                    const float* xp = data + ((size_t)t * BATCH + b) * IN_DIM;
                    #pragma unroll
                    for (int i = 0; i < IN_DIM; ++i) {
                        float xv = xp[i];
                        gi += w0[i] * xv; gf += w1[i] * xv; gg += w2[i] * xv; go += w3[i] * xv;
                    }
                    if (t < lenr[r]) {
                        float cnew = sigf(gf) * creg[r] + sigf(gi) * tanhft(gg);
                        creg[r] = cnew;
                        hreg[r] = sigf(go) * tanhft(cnew);
                    }
                    hcur[b * HID + j] = (_Float16)hreg[r];
                }
            }
        } else if (bid < 192) {
            if (e >= 1 && e <= T_STEPS) {
                const int t = e - 1;
                const int j0 = (bid - 64) * 8, mb = wv * 16;
                const _Float16* h1p = buf1 + ((e + 1) & 1) * (BATCH * HID);  // h1[e-1]
                const _Float16* h2p = buf2 + (e & 1) * (BATCH * HID);        // h2[e-2]
                _Float16*       h2c = buf2 + ((e + 1) & 1) * (BATCH * HID);  // h2[e-1]
                floatx4 acc0 = {0,0,0,0}, acc1 = {0,0,0,0};
                const _Float16* a1 = h1p + (mb + lr) * HID + lg * 8;
                const _Float16* a2 = h2p + (mb + lr) * HID + lg * 8;
                #pragma unroll 4
                for (int kt = 0; kt < 32; ++kt) {
                    half8 a = *(const half8*)(a1 + kt * 32);
                    const int kB = (kt * 32 + lg * 8) * 2;
                    acc0 = mfma16(a, *(const half8*)(smem + swz( 0 + lr, kB, 4096)), acc0);
                    acc1 = mfma16(a, *(const half8*)(smem + swz(16 + lr, kB, 4096)), acc1);
                }
                #pragma unroll 4
                for (int kt = 0; kt < 32; ++kt) {
                    half8 a = *(const half8*)(a2 + kt * 32);
                    const int kB = (2048 + (kt * 32 + lg * 8)) * 2;
                    acc0 = mfma16(a, *(const half8*)(smem + swz( 0 + lr, kB, 4096)), acc0);
                    acc1 = mfma16(a, *(const half8*)(smem + swz(16 + lr, kB, 4096)), acc1);
                }
                #pragma unroll
                for (int r = 0; r < 4; ++r) {
                    float v0 = acc0[r] + b0v;          // lr<8: i, lr>=8: f
                    float v1 = acc1[r] + b1v;          // lr<8: g, lr>=8: o
                    float p0 = __shfl_xor(v0, 8);
                    float p1 = __shfl_xor(v1, 8);
                    if ((lr & 8) == 0) {
                        const int b = mb + lg * 4 + r;
                        if (t < lenr[r]) {
                            float cnew = sigf(p0) * creg[r] + sigf(v0) * tanhft(v1);
                            creg[r] = cnew;
                            hreg[r] = sigf(p1) * tanhft(cnew);
                        }
                        h2c[b * HID + j0 + (lr & 7)] = (_Float16)hreg[r];
                    }
                }
            }
        } else {
            if (e >= 2) {
                const int t = e - 2;
                const _Float16* h2 = buf2 + (e & 1) * (BATCH * HID);  // h2[e-2]
                const float* wlds = (const float*)smem;
                const int ow = bid - 192;
                #pragma unroll
                for (int s = 0; s < 2; ++s) {
                    const int b = ow * 8 + wv * 2 + s;
                    const bool valid = t < lenr[s];
                    float p0 = 0, p1 = 0, p2 = 0, p3 = 0, p4 = 0;
                    if (valid) {
                        const _Float16* hp = h2 + b * HID;
                        for (int ch = 0; ch < 16; ++ch) {
                            int jj = ch * 64 + lane;
                            float hv = (float)hp[jj];
                            p0 += hv * wlds[jj];
                            p1 += hv * wlds[HID + jj];
                            p2 += hv * wlds[2 * HID + jj];
                            p3 += hv * wlds[3 * HID + jj];
                            p4 += hv * wlds[4 * HID + jj];
                        }
                        #pragma unroll
                        for (int o = 32; o; o >>= 1) {
                            p0 += __shfl_xor(p0, o); p1 += __shfl_xor(p1, o);
                            p2 += __shfl_xor(p2, o); p3 += __shfl_xor(p3, o);
                            p4 += __shfl_xor(p4, o);
                        }
                    }
                    if (lane == 0) {
                        float l0 = p0 + bout[0], l1 = p1 + bout[1];
                        float l2 = p2 + bout[2], l3 = p3 + bout[3], l4 = p4 + bout[4];
                        float m  = fmaxf(l2, fmaxf(l3, l4));
                        float e2 = __expf(l2 - m), e3 = __expf(l3 - m), e4 = __expf(l4 - m);
                        float inv = 1.f / (e2 + e3 + e4);
                        float* op = out + ((size_t)t * BATCH + b) * IN_DIM;
                        op[0] = l0; op[1] = l1; op[2] = e2 * inv; op[3] = e3 * inv; op[4] = e4 * inv;
                    }
                }
            }
        }
        grid.sync();
    }
}

extern "C" void kernel_launch(void* const* d_in, const int* in_sizes, int n_in,
                              void* d_out, int out_size, void* d_ws, size_t ws_size,
                              hipStream_t stream)
{
    if (ws_size < WS_STATE) return;   // fail clean, never scribble OOB

    static bool attr_set = false;     // idempotent host-side attr (not a stream op)
    if (!attr_set) {
        hipFuncSetAttribute((const void*)lstm_persistent,
                            hipFuncAttributeMaxDynamicSharedMemorySize, (int)LDS_BYTES);
        attr_set = true;
    }

    void* ws   = d_ws;
    void* data = d_in[0];  void* lens = d_in[1];
    void* Wih0 = d_in[2];  void* Whh0 = d_in[3];
    void* bih0 = d_in[4];  void* bhh0 = d_in[5];
    void* Wih1 = d_in[6];  void* Whh1 = d_in[7];
    void* bih1 = d_in[8];  void* bhh1 = d_in[9];
    void* Wout = d_in[10]; void* bout = d_in[11];
    void* outp = d_out;

    // zero h ping-pong state (ws is re-poisoned 0xAA before every timed call)
    hipMemsetAsync(d_ws, 0, WS_STATE, stream);

    void* args[] = { &ws, &data, &lens, &Wih0, &Whh0, &bih0, &bhh0,
                     &Wih1, &Whh1, &bih1, &bhh1, &Wout, &bout, &outp };
    hipLaunchCooperativeKernel((const void*)lstm_persistent,
                               dim3(NWG), dim3(256), args, LDS_BYTES, stream);
}

// Round 9
// 20545.299 us; speedup vs baseline: 1.6886x; 1.6886x over previous
//
#include <hip/hip_runtime.h>

typedef __attribute__((ext_vector_type(8))) _Float16 half8;
typedef __attribute__((ext_vector_type(4))) _Float16 half4;
typedef __attribute__((ext_vector_type(4))) float floatx4;

constexpr int T_STEPS = 1024, BATCH = 64, HID = 1024, IN_DIM = 5;
constexpr int NWG = 200;                       // 64 L1 + 128 L2 + 8 OUT
constexpr size_t LDS_BYTES = 131072;           // 128 KiB per WG (weights)

// Workspace: h ping-pong buffers + mailbox (c lives in registers).
constexpr size_t O_B1 = 0;                                   // h1 fp16 [2][64][1024]
constexpr size_t O_B2 = O_B1 + 2 * (size_t)BATCH * HID * 2;  // h2 fp16 [2][64][1024]
constexpr size_t O_MB = O_B2 + 2 * (size_t)BATCH * HID * 2;  // mailbox int[256]
constexpr size_t WS_NEED = O_MB + 256 * 4;

__device__ __forceinline__ float sigf(float x)   { return 1.f / (1.f + __expf(-x)); }
__device__ __forceinline__ float tanhft(float x) { return 2.f / (1.f + __expf(-2.f * x)) - 1.f; }
__device__ __forceinline__ floatx4 mfma16(half8 a, half8 b, floatx4 c) {
    return __builtin_amdgcn_mfma_f32_16x16x32_f16(a, b, c, 0, 0, 0);
}
__device__ __forceinline__ int swz(int row, int kByte, int rowStrideB) {
    return row * rowStrideB + (kByte ^ ((row & 7) << 4));
}
// Write-through stores (sc0 sc1): land at the coherence point (L3), never dirty in L2.
__device__ __forceinline__ void st_h16(_Float16* p, float v) {
    _Float16 h = (_Float16)v;
    unsigned int u = (unsigned int)__builtin_bit_cast(unsigned short, h);
    asm volatile("global_store_short %0, %1, off sc0 sc1" :: "v"(p), "v"(u) : "memory");
}
__device__ __forceinline__ void st_f32(float* p, float v) {
    asm volatile("global_store_dword %0, %1, off sc0 sc1" :: "v"(p), "v"(v) : "memory");
}

__global__ void __launch_bounds__(256) lstm_persistent(
    char* __restrict__ ws,
    const float* __restrict__ data, const int* __restrict__ lens,
    const float* __restrict__ Wih0, const float* __restrict__ Whh0,
    const float* __restrict__ bih0, const float* __restrict__ bhh0,
    const float* __restrict__ Wih1, const float* __restrict__ Whh1,
    const float* __restrict__ bih1, const float* __restrict__ bhh1,
    const float* __restrict__ Wout, const float* __restrict__ bout,
    float* __restrict__ out)
{
    extern __shared__ char smem[];

    _Float16* buf1 = (_Float16*)(ws + O_B1);
    _Float16* buf2 = (_Float16*)(ws + O_B2);
    int*      mbox = (int*)(ws + O_MB);

    const int bid  = blockIdx.x;
    const int tid  = threadIdx.x;
    const int lane = tid & 63;
    const int wv   = tid >> 6;
    const int lr   = lane & 15, lg = lane >> 4;

    // ---------------- init: stage weights into LDS, biases/x-weights into regs ----------------
    float creg[4] = {0.f, 0.f, 0.f, 0.f};
    float hreg[4] = {0.f, 0.f, 0.f, 0.f};
    int   lenr[4];
    float b0v = 0, b1v = 0, b2v = 0, b3v = 0;
    float w0[IN_DIM], w1[IN_DIM], w2[IN_DIM], w3[IN_DIM];
    float bo[IN_DIM];

    if (bid < 64) {
        // L1 WG: 16 units j0, 64 weight rows (r = g*16+u), K=1024, LDS [64][1024] fp16.
        const int j0 = bid * 16;
        for (int i = tid * 4; i < 64 * HID; i += 256 * 4) {
            int r = i >> 10, k = i & 1023;
            int gr = (r >> 4) * HID + j0 + (r & 15);
            const float4 w = *(const float4*)&Whh0[(size_t)gr * HID + k];
            half4 h4 = { (_Float16)w.x, (_Float16)w.y, (_Float16)w.z, (_Float16)w.w };
            *(half4*)(smem + swz(r, k * 2, 2048)) = h4;
        }
        const int j = j0 + lr;
        b0v = bih0[j] + bhh0[j];
        b1v = bih0[HID + j] + bhh0[HID + j];
        b2v = bih0[2 * HID + j] + bhh0[2 * HID + j];
        b3v = bih0[3 * HID + j] + bhh0[3 * HID + j];
        #pragma unroll
        for (int i = 0; i < IN_DIM; ++i) {
            w0[i] = Wih0[(0 * HID + j) * IN_DIM + i];
            w1[i] = Wih0[(1 * HID + j) * IN_DIM + i];
            w2[i] = Wih0[(2 * HID + j) * IN_DIM + i];
            w3[i] = Wih0[(3 * HID + j) * IN_DIM + i];
        }
        const int mb = wv * 16;
        #pragma unroll
        for (int r = 0; r < 4; ++r) lenr[r] = lens[mb + lg * 4 + r];
    } else if (bid < 192) {
        // L2 WG: 8 units j0, 32 rows, K=2048 ([Wih1|Whh1]), LDS [32][2048] fp16.
        const int j0 = (bid - 64) * 8;
        for (int i = tid * 4; i < 32 * 2048; i += 256 * 4) {
            int r = i >> 11, k = i & 2047;
            int gr = (r >> 3) * HID + j0 + (r & 7);
            const float* src = (k < HID) ? &Wih1[(size_t)gr * HID + k]
                                         : &Whh1[(size_t)gr * HID + (k - HID)];
            const float4 w = *(const float4*)src;
            half4 h4 = { (_Float16)w.x, (_Float16)w.y, (_Float16)w.z, (_Float16)w.w };
            *(half4*)(smem + swz(r, k * 2, 4096)) = h4;
        }
        {
            int g0 = lr >> 3, u = lr & 7;
            b0v = bih1[g0 * HID + j0 + u] + bhh1[g0 * HID + j0 + u];
            b1v = bih1[(2 + g0) * HID + j0 + u] + bhh1[(2 + g0) * HID + j0 + u];
        }
        const int mb = wv * 16;
        #pragma unroll
        for (int r = 0; r < 4; ++r) lenr[r] = lens[mb + lg * 4 + r];
    } else {
        // OUT WG: stage Wout (5x1024 f32 = 20KB) into LDS; biases into regs.
        float* wlds = (float*)smem;
        for (int i = tid; i < IN_DIM * HID; i += 256) wlds[i] = Wout[i];
        const int ow = bid - 192;
        lenr[0] = lens[ow * 8 + wv * 2 + 0];
        lenr[1] = lens[ow * 8 + wv * 2 + 1];
        #pragma unroll
        for (int i = 0; i < IN_DIM; ++i) bo[i] = bout[i];
    }
    __syncthreads();

    // ---------------- time loop: epoch e = L1 step e, L2 step e-1, OUT step e-2 ----------------
    for (int e = 0; e <= T_STEPS + 1; ++e) {
        if (bid < 64) {
            if (e < T_STEPS) {
                const int t = e;
                const int j0 = bid * 16, mb = wv * 16;
                const _Float16* hprev = buf1 + ((e + 1) & 1) * (BATCH * HID);
                _Float16*       hcur  = buf1 + (e & 1) * (BATCH * HID);
                floatx4 acc0 = {0,0,0,0}, acc1 = {0,0,0,0}, acc2 = {0,0,0,0}, acc3 = {0,0,0,0};
                if (e > 0) {   // e==0: h1[-1]=0 -> accs stay zero (never read poisoned buf)
                    const _Float16* ap = hprev + (mb + lr) * HID + lg * 8;
                    #pragma unroll 4
                    for (int kt = 0; kt < 32; ++kt) {
                        half8 a = *(const half8*)(ap + kt * 32);
                        const int kB = (kt * 32 + lg * 8) * 2;
                        acc0 = mfma16(a, *(const half8*)(smem + swz( 0 + lr, kB, 2048)), acc0);
                        acc1 = mfma16(a, *(const half8*)(smem + swz(16 + lr, kB, 2048)), acc1);
                        acc2 = mfma16(a, *(const half8*)(smem + swz(32 + lr, kB, 2048)), acc2);
                        acc3 = mfma16(a, *(const half8*)(smem + swz(48 + lr, kB, 2048)), acc3);
                    }
                }
                const int j = j0 + lr;
                #pragma unroll
                for (int r = 0; r < 4; ++r) {
                    const int b = mb + lg * 4 + r;
                    float gi = acc0[r] + b0v, gf = acc1[r] + b1v;
                    float gg = acc2[r] + b2v, go = acc3[r] + b3v;
                    const float* xp = data + ((size_t)t * BATCH + b) * IN_DIM;
                    #pragma unroll
                    for (int i = 0; i < IN_DIM; ++i) {
                        float xv = xp[i];
                        gi += w0[i] * xv; gf += w1[i] * xv; gg += w2[i] * xv; go += w3[i] * xv;
                    }
                    if (t < lenr[r]) {
                        float cnew = sigf(gf) * creg[r] + sigf(gi) * tanhft(gg);
                        creg[r] = cnew;
                        hreg[r] = sigf(go) * tanhft(cnew);
                    }
                    st_h16(&hcur[b * HID + j], hreg[r]);
                }
            }
        } else if (bid < 192) {
            if (e >= 1 && e <= T_STEPS) {
                const int t = e - 1;
                const int j0 = (bid - 64) * 8, mb = wv * 16;
                const _Float16* h1p = buf1 + ((e + 1) & 1) * (BATCH * HID);  // h1[e-1]
                const _Float16* h2p = buf2 + (e & 1) * (BATCH * HID);        // h2[e-2]
                _Float16*       h2c = buf2 + ((e + 1) & 1) * (BATCH * HID);  // h2[e-1]
                // 4 independent MFMA chains (fills matrix pipe at 1 wave/SIMD)
                floatx4 acc0 = {0,0,0,0}, acc1 = {0,0,0,0}, acc2 = {0,0,0,0}, acc3 = {0,0,0,0};
                {
                    const _Float16* a1 = h1p + (mb + lr) * HID + lg * 8;
                    #pragma unroll 4
                    for (int kt = 0; kt < 32; ++kt) {
                        half8 a = *(const half8*)(a1 + kt * 32);
                        const int kB = (kt * 32 + lg * 8) * 2;
                        acc0 = mfma16(a, *(const half8*)(smem + swz( 0 + lr, kB, 4096)), acc0);
                        acc1 = mfma16(a, *(const half8*)(smem + swz(16 + lr, kB, 4096)), acc1);
                    }
                }
                if (e > 1) {   // e==1: h2[-1]=0 -> skip (never read poisoned buf)
                    const _Float16* a2 = h2p + (mb + lr) * HID + lg * 8;
                    #pragma unroll 4
                    for (int kt = 0; kt < 32; ++kt) {
                        half8 a = *(const half8*)(a2 + kt * 32);
                        // Whh1 half = elements 1024..2047 of the combined row
                        // (was 2048+x: next-row/OOB-LDS read -> round-3 absmax 5.4e-3, round-6 NaN)
                        const int kB = (1024 + (kt * 32 + lg * 8)) * 2;
                        acc2 = mfma16(a, *(const half8*)(smem + swz( 0 + lr, kB, 4096)), acc2);
                        acc3 = mfma16(a, *(const half8*)(smem + swz(16 + lr, kB, 4096)), acc3);
                    }
                }
                #pragma unroll
                for (int r = 0; r < 4; ++r) {
                    float v0 = acc0[r] + acc2[r] + b0v;   // lr<8: i, lr>=8: f
                    float v1 = acc1[r] + acc3[r] + b1v;   // lr<8: g, lr>=8: o
                    float p0 = __shfl_xor(v0, 8);
                    float p1 = __shfl_xor(v1, 8);
                    if ((lr & 8) == 0) {
                        const int b = mb + lg * 4 + r;
                        if (t < lenr[r]) {
                            float cnew = sigf(p0) * creg[r] + sigf(v0) * tanhft(v1);
                            creg[r] = cnew;
                            hreg[r] = sigf(p1) * tanhft(cnew);
                        }
                        st_h16(&h2c[b * HID + j0 + (lr & 7)], hreg[r]);
                    }
                }
            }
        } else {
            if (e >= 2) {
                const int t = e - 2;
                const _Float16* h2 = buf2 + (e & 1) * (BATCH * HID);  // h2[e-2]
                const float* wlds = (const float*)smem;
                const int ow = bid - 192;
                #pragma unroll
                for (int s = 0; s < 2; ++s) {
                    const int b = ow * 8 + wv * 2 + s;
                    const bool valid = t < lenr[s];
                    float p0 = 0, p1 = 0, p2 = 0, p3 = 0, p4 = 0;
                    if (valid) {   // wave-uniform (same b across wave)
                        const _Float16* hp = h2 + b * HID;
                        half8 v0 = *(const half8*)(hp + lane * 8);
                        half8 v1 = *(const half8*)(hp + 512 + lane * 8);
                        #pragma unroll
                        for (int m = 0; m < 8; ++m) {
                            int ja = lane * 8 + m, jb = 512 + lane * 8 + m;
                            float ha = (float)v0[m], hb = (float)v1[m];
                            p0 += ha * wlds[ja] + hb * wlds[jb];
                            p1 += ha * wlds[HID + ja] + hb * wlds[HID + jb];
                            p2 += ha * wlds[2 * HID + ja] + hb * wlds[2 * HID + jb];
                            p3 += ha * wlds[3 * HID + ja] + hb * wlds[3 * HID + jb];
                            p4 += ha * wlds[4 * HID + ja] + hb * wlds[4 * HID + jb];
                        }
                        #pragma unroll
                        for (int o = 32; o; o >>= 1) {
                            p0 += __shfl_xor(p0, o); p1 += __shfl_xor(p1, o);
                            p2 += __shfl_xor(p2, o); p3 += __shfl_xor(p3, o);
                            p4 += __shfl_xor(p4, o);
                        }
                    }
                    if (lane == 0) {
                        float l0 = p0 + bo[0], l1 = p1 + bo[1];
                        float l2 = p2 + bo[2], l3 = p3 + bo[3], l4 = p4 + bo[4];
                        float m  = fmaxf(l2, fmaxf(l3, l4));
                        float e2 = __expf(l2 - m), e3 = __expf(l3 - m), e4 = __expf(l4 - m);
                        float inv = 1.f / (e2 + e3 + e4);
                        float* op = out + ((size_t)t * BATCH + b) * IN_DIM;
                        st_f32(op + 0, l0); st_f32(op + 1, l1);
                        st_f32(op + 2, e2 * inv); st_f32(op + 3, e3 * inv); st_f32(op + 4, e4 * inv);
                    }
                }
            }
        }

        // ---------------- epoch barrier (mailbox, no cache flushes in hot path) ----------------
        if (e < T_STEPS + 1) {
            const int target = e + 1;
            asm volatile("s_waitcnt vmcnt(0)" ::: "memory");   // h stores reached L3
            __syncthreads();
            if (tid == 0)
                __hip_atomic_store(&mbox[bid], target, __ATOMIC_RELAXED, __HIP_MEMORY_SCOPE_AGENT);
            if (wv == 0) {
                for (;;) {
                    int m0 = __hip_atomic_load(&mbox[lane],       __ATOMIC_RELAXED, __HIP_MEMORY_SCOPE_AGENT);
                    int m1 = __hip_atomic_load(&mbox[64 + lane],  __ATOMIC_RELAXED, __HIP_MEMORY_SCOPE_AGENT);
                    int m2 = __hip_atomic_load(&mbox[128 + lane], __ATOMIC_RELAXED, __HIP_MEMORY_SCOPE_AGENT);
                    int m3 = (lane < NWG - 192)
                           ? __hip_atomic_load(&mbox[192 + lane], __ATOMIC_RELAXED, __HIP_MEMORY_SCOPE_AGENT)
                           : target;
                    int mn = min(min(m0, m1), min(m2, m3));
                    #pragma unroll
                    for (int o = 32; o; o >>= 1) mn = min(mn, __shfl_xor(mn, o));
                    if (mn >= target) break;
                }
            }
            __syncthreads();
            // drop clean stale h lines from this XCD's L2; next reads re-fill from L3
            __builtin_amdgcn_fence(__ATOMIC_ACQUIRE, "agent");
        }
    }
}

extern "C" void kernel_launch(void* const* d_in, const int* in_sizes, int n_in,
                              void* d_out, int out_size, void* d_ws, size_t ws_size,
                              hipStream_t stream)
{
    if (ws_size < WS_NEED) return;   // fail clean, never scribble OOB

    (void)hipFuncSetAttribute((const void*)lstm_persistent,
                              hipFuncAttributeMaxDynamicSharedMemorySize, (int)LDS_BYTES);

    void* ws   = d_ws;
    void* data = d_in[0];  void* lens = d_in[1];
    void* Wih0 = d_in[2];  void* Whh0 = d_in[3];
    void* bih0 = d_in[4];  void* bhh0 = d_in[5];
    void* Wih1 = d_in[6];  void* Whh1 = d_in[7];
    void* bih1 = d_in[8];  void* bhh1 = d_in[9];
    void* Wout = d_in[10]; void* bout = d_in[11];
    void* outp = d_out;

    void* args[] = { &ws, &data, &lens, &Wih0, &Whh0, &bih0, &bhh0,
                     &Wih1, &Whh1, &bih1, &bhh1, &Wout, &bout, &outp };
    (void)hipLaunchCooperativeKernel((const void*)lstm_persistent,
                                     dim3(NWG), dim3(256), args, LDS_BYTES, stream);
}